// Round 12
// baseline (146.360 us; speedup 1.0000x reference)
//
#include <hip/hip_runtime.h>
#include <stdint.h>

#define B_   2048
#define C_   1000
#define N2   4096
#define D_   256
#define JSPLIT 32
#define IBLK   256                   // i-rows per k4 block (8 waves x 32)
#define NGRP   (N2 / IBLK)           // 16 i-groups
#define JRNG   (N2 / JSPLIT)         // 128 j-rows per block, staged once

typedef float  f32x4  __attribute__((ext_vector_type(4)));
typedef short  short8 __attribute__((ext_vector_type(8)));

__device__ __forceinline__ float waveSum(float v){
#pragma unroll
  for (int o = 32; o; o >>= 1) v += __shfl_xor(v, o, 64);
  return v;
}
__device__ __forceinline__ float waveMax(float v){
#pragma unroll
  for (int o = 32; o; o >>= 1) v = fmaxf(v, __shfl_xor(v, o, 64));
  return v;
}
__device__ __forceinline__ unsigned short f2bf(float f){
  uint32_t u = __float_as_uint(f);
  u += 0x7fffu + ((u >> 16) & 1u);           // RNE
  return (unsigned short)(u >> 16);
}
__device__ __forceinline__ float bf2f(unsigned short h){
  return __uint_as_float(((uint32_t)h) << 16);
}

// ---- Kernel 1: wave-per-row softmax + tp + new_target (single global pass) ---
__global__ __launch_bounds__(256) void k1_softmax_tp(
    const float* __restrict__ outputs, const float* __restrict__ Y,
    float* __restrict__ nt, int* __restrict__ tp, int* __restrict__ tickets)
{
  if (blockIdx.x == 0 && threadIdx.x < NGRP + 1)
    tickets[threadIdx.x] = 0;                // reset k4's group+final tickets
  const int w = threadIdx.x >> 6, l = threadIdx.x & 63;
  const int i = blockIdx.x * 4 + w;                    // 0..B_-1
  const float4* o4 = (const float4*)(outputs + (size_t)i * C_);
  const float4* y4 = (const float4*)(Y + (size_t)i * C_);

  float4 ov[4], yv[4];
#pragma unroll
  for (int q = 0; q < 4; ++q){
    int idx = q * 64 + l;
    if (idx < 250){ ov[q] = o4[idx]; yv[q] = y4[idx]; }
    else { ov[q] = make_float4(-3.4e38f,-3.4e38f,-3.4e38f,-3.4e38f);
           yv[q] = make_float4(0.f,0.f,0.f,0.f); }
  }

  float m = -3.4e38f;
#pragma unroll
  for (int q = 0; q < 4; ++q)
    m = fmaxf(m, fmaxf(fmaxf(ov[q].x, ov[q].y), fmaxf(ov[q].z, ov[q].w)));
  m = waveMax(m);

  float s = 0.f, bv = -3.4e38f; int bi = 0x7fffffff;
#pragma unroll
  for (int q = 0; q < 4; ++q){
    int c0 = (q * 64 + l) * 4;
    const float* op = (const float*)&ov[q];
    const float* yp = (const float*)&yv[q];
#pragma unroll
    for (int r = 0; r < 4; ++r){
      if (yp[r] > 0.f){
        float oc = op[r];
        s += __expf(oc - m);
        if (oc > bv || (oc == bv && c0 + r < bi)){ bv = oc; bi = c0 + r; }
      }
    }
  }
  s = waveSum(s);
#pragma unroll
  for (int off = 32; off; off >>= 1){
    float ovv = __shfl_xor(bv, off, 64);
    int   oii = __shfl_xor(bi, off, 64);
    if (ovv > bv || (ovv == bv && oii < bi)){ bv = ovv; bi = oii; }
  }

  const float inv = 1.f / s;
  float4* nt4 = (float4*)(nt + (size_t)i * C_);        // i*1000 % 4 == 0: aligned
#pragma unroll
  for (int q = 0; q < 4; ++q){
    int idx = q * 64 + l;
    if (idx < 250){
      const float* op = (const float*)&ov[q];
      const float* yp = (const float*)&yv[q];
      float4 res;
      res.x = (yp[0] > 0.f) ? __expf(op[0] - m) * inv : 0.f;
      res.y = (yp[1] > 0.f) ? __expf(op[1] - m) * inv : 0.f;
      res.z = (yp[2] > 0.f) ? __expf(op[2] - m) * inv : 0.f;
      res.w = (yp[3] > 0.f) ? __expf(op[3] - m) * inv : 0.f;
      nt4[idx] = res;
    }
  }
  if (l == 0){
    if (bi < 0 || bi >= C_) bi = 0;
    tp[i] = bi;
  }
}

// ---- Kernel 3: maskB (bf16) + rowsum + cf->bf16; LDS-staged row gathers ------
__global__ __launch_bounds__(256) void k3_mask(
    const float* __restrict__ Y, const float* __restrict__ ps,
    const int* __restrict__ tp,
    const float* __restrict__ feat, unsigned short* __restrict__ cfb,
    unsigned short* __restrict__ maskB, float* __restrict__ rowsum)
{
  __shared__ int h[C_];
  __shared__ float4 yrow4[250], prow4[250];
  const float* yr = (const float*)yrow4;
  const float* pr = (const float*)prow4;
  const int i = blockIdx.x, t = threadIdx.x;

  // fold: convert flat cfb elements [i*512, i*512+512), vectorized (t<128)
  if (t < 128){
    int idx0 = i * 512 + t * 4;
    int r = idx0 >> 8, d = idx0 & 255;
    int src = (r < B_) ? (r * 512 + d) : ((r - B_) * 512 + 256 + d);
    float4 f = *reinterpret_cast<const float4*>(feat + src);
    uint2 pk;
    pk.x = (uint32_t)f2bf(f.x) | ((uint32_t)f2bf(f.y) << 16);
    pk.y = (uint32_t)f2bf(f.z) | ((uint32_t)f2bf(f.w) << 16);
    *reinterpret_cast<uint2*>(cfb + idx0) = pk;
  }

  for (int c = t; c < C_; c += 256) h[c] = 0;
  __syncthreads();
  // coalesced row staging into LDS (float4)
  if (t < 250){
    yrow4[t] = ((const float4*)(Y  + (size_t)i * C_))[t];
    prow4[t] = ((const float4*)(ps + (size_t)i * C_))[t];
  }
  const int4 t0 = ((const int4*)tp)[t];          // j = 4t .. 4t+3
  const int4 t1 = ((const int4*)tp)[t + 256];    // j = 1024+4t ..
  atomicAdd(&h[t0.x], 1); atomicAdd(&h[t0.y], 1);
  atomicAdd(&h[t0.z], 1); atomicAdd(&h[t0.w], 1);
  atomicAdd(&h[t1.x], 1); atomicAdd(&h[t1.y], 1);
  atomicAdd(&h[t1.z], 1); atomicAdd(&h[t1.w], 1);
  __syncthreads();

  float v0[4], v1[4];
  v0[0] = yr[t0.x] * pr[t0.x] / (float)h[t0.x];
  v0[1] = yr[t0.y] * pr[t0.y] / (float)h[t0.y];
  v0[2] = yr[t0.z] * pr[t0.z] / (float)h[t0.z];
  v0[3] = yr[t0.w] * pr[t0.w] / (float)h[t0.w];
  v1[0] = yr[t1.x] * pr[t1.x] / (float)h[t1.x];
  v1[1] = yr[t1.y] * pr[t1.y] / (float)h[t1.y];
  v1[2] = yr[t1.z] * pr[t1.z] / (float)h[t1.z];
  v1[3] = yr[t1.w] * pr[t1.w] / (float)h[t1.w];

  uint2 pk0, pk1;
  pk0.x = (uint32_t)f2bf(v0[0]) | ((uint32_t)f2bf(v0[1]) << 16);
  pk0.y = (uint32_t)f2bf(v0[2]) | ((uint32_t)f2bf(v0[3]) << 16);
  pk1.x = (uint32_t)f2bf(v1[0]) | ((uint32_t)f2bf(v1[1]) << 16);
  pk1.y = (uint32_t)f2bf(v1[2]) | ((uint32_t)f2bf(v1[3]) << 16);
  ((uint2*)(maskB + (size_t)i * B_))[t]       = pk0;
  ((uint2*)(maskB + (size_t)i * B_))[t + 256] = pk1;

  float loc = (v0[0] + v0[1] + v0[2] + v0[3]) + (v1[0] + v1[1] + v1[2] + v1[3]);
  loc = waveSum(loc);
  __shared__ float sr[4];
  if ((t & 63) == 0) sr[t >> 6] = loc;
  __syncthreads();
  if (t == 0) rowsum[i] = sr[0] + sr[1] + sr[2] + sr[3];
}

// ---- Kernel 4: fused bf16 MFMA GEMM + row reductions + FINAL LOSS ------------
// grid (NGRP, JSPLIT), 512 threads (8 waves). GEMM body unchanged from r9/r11.
// __launch_bounds__(512, 2): r10/r11 ran at VGPR_Count=64 (allocator treated
// the old ",4" as 8 waves/SIMD -> 64-reg cap) which spilled the 64-VGPR afrag
// arrays to scratch (MfmaUtil 2.5%). ",2" guarantees a >=128-reg budget;
// occupancy is LDS-limited to 2 blocks/CU regardless, so nothing is lost.
__global__ __launch_bounds__(512, 2) void k4_gemm(
    const unsigned short* __restrict__ cfb, const unsigned short* __restrict__ maskB,
    float2* __restrict__ gES, const float* __restrict__ rowsum,
    float* __restrict__ partial, int* __restrict__ tickets,
    float* __restrict__ out)
{
  __shared__ uint4 lds4[4096];               // 128 rows x 512 B = 64 KiB
  __shared__ int   slast;
  __shared__ float sr8[8];
  const int tid = threadIdx.x;
  const int w = tid >> 6;
  const int l = tid & 63;
  const int gid = blockIdx.x;                // i-group 0..NGRP-1
  const int Ib = gid * IBLK;
  const int Jb = blockIdx.y * JRNG;
  const int iA0 = Ib + w * 32 + (l & 15);           // A-tile0 row this lane loads
  const int irow0 = Ib + w * 32 + ((l >> 4) << 2);  // D-tile0 first output i-row

  // async global->LDS staging (dwordx4), pre-swizzled source, linear LDS dest
#pragma unroll
  for (int rep = 0; rep < 8; ++rep){
    int q    = tid + (rep << 9);
    int rowl = q >> 5;
    int c16  = (q & 31) ^ (rowl & 7);        // pre-swizzled source slot
    const unsigned short* gsrc =
        cfb + ((size_t)(Jb + rowl) << 8) + (c16 << 3);
    uint4* ldst = &lds4[(rep << 9) + (w << 6)];      // wave-uniform base
    __builtin_amdgcn_global_load_lds(
        (const __attribute__((address_space(1))) void*)gsrc,
        (__attribute__((address_space(3))) void*)ldst, 16, 0, 0);
  }

  short8 afrag0[8], afrag1[8];
#pragma unroll
  for (int kk = 0; kk < 8; ++kk){
    afrag0[kk] = *reinterpret_cast<const short8*>(
        cfb + ((size_t)iA0 << 8) + (kk << 5) + ((l >> 4) << 3));
    afrag1[kk] = *reinterpret_cast<const short8*>(
        cfb + ((size_t)(iA0 + 16) << 8) + (kk << 5) + ((l >> 4) << 3));
  }

  __syncthreads();                           // the ONLY compute barrier

  float E0[4]  = {0.f,0.f,0.f,0.f}, S10[4] = {0.f,0.f,0.f,0.f};
  float E1[4]  = {0.f,0.f,0.f,0.f}, S11[4] = {0.f,0.f,0.f,0.f};

#pragma unroll
  for (int s = 0; s < JRNG / 16; ++s){       // 8 independent steps
    f32x4 a0 = {0.f,0.f,0.f,0.f};
    f32x4 a1 = {0.f,0.f,0.f,0.f};
    const int brow = s * 16 + (l & 15);      // j-row of LDS tile (B operand)
#pragma unroll
    for (int kk = 0; kk < 8; ++kk){
      int idx16 = brow * 32 + ((kk * 4 + (l >> 4)) ^ (l & 7));
      short8 bfr = *reinterpret_cast<const short8*>(&lds4[idx16]);
      a0 = __builtin_amdgcn_mfma_f32_16x16x32_bf16(afrag0[kk], bfr, a0, 0, 0, 0);
      a1 = __builtin_amdgcn_mfma_f32_16x16x32_bf16(afrag1[kk], bfr, a1, 0, 0, 0);
    }
    const int j  = Jb + s * 16 + (l & 15);
    const int jp = j & (B_ - 1);
#pragma unroll
    for (int r = 0; r < 4; ++r){
      {
        const int ir  = irow0 + r;
        const int ipr = ir & (B_ - 1);
        float mv = bf2f(maskB[(size_t)ipr * B_ + jp]);   // coalesced over l&15
        float d = a0[r] * 10.f;              // adc = dot / T
        if (j != ir){                        // skip exact diagonal
          E0[r]  += __expf(d - 10.f);        // M = 10 (row max = diagonal)
          S10[r] += mv * d;
        }
      }
      {
        const int ir  = irow0 + 16 + r;
        const int ipr = ir & (B_ - 1);
        float mv = bf2f(maskB[(size_t)ipr * B_ + jp]);
        float d = a1[r] * 10.f;
        if (j != ir){
          E1[r]  += __expf(d - 10.f);
          S11[r] += mv * d;
        }
      }
    }
  }

  // reduce across the 16 lanes of each quadrant (same output i-row set)
#pragma unroll
  for (int r = 0; r < 4; ++r){
    float e0 = E0[r], s0 = S10[r], e1 = E1[r], s1 = S11[r];
#pragma unroll
    for (int off = 1; off < 16; off <<= 1){
      e0 += __shfl_xor(e0, off, 64);  s0 += __shfl_xor(s0, off, 64);
      e1 += __shfl_xor(e1, off, 64);  s1 += __shfl_xor(s1, off, 64);
    }
    if ((l & 15) == 0){
      gES[(size_t)(irow0 + r)      * JSPLIT + blockIdx.y] = make_float2(e0, s0);
      gES[(size_t)(irow0 + 16 + r) * JSPLIT + blockIdx.y] = make_float2(e1, s1);
    }
  }

  // ---- fused k5: last j-split block of this i-group combines the group ------
  __threadfence();                           // release gES writes device-wide
  if (tid == 0)
    slast = (atomicAdd(&tickets[gid], 1) == JSPLIT - 1);
  __syncthreads();
  if (!slast) return;
  __threadfence();                           // acquire other blocks' gES writes

  float loc = 0.f;
  if (tid < IBLK){
    const int i = Ib + tid;                  // this group's row
    const float2* vv = gES + (size_t)i * JSPLIT;
    float E = 0.f, S1 = 0.f;
#pragma unroll 4
    for (int q = 0; q < JSPLIT; ++q){
      float2 t = vv[q];
      E  += t.x;
      S1 += t.y;
    }
    int ipp = i & (B_ - 1);
    float msum = 2.f * rowsum[ipp] - bf2f(maskB[(size_t)ipp * B_ + ipp]);
    loc = S1 - msum * (10.f + __logf(E));    // contrib with M=10
  }
  loc = waveSum(loc);
  if ((tid & 63) == 0) sr8[tid >> 6] = loc;
  __syncthreads();
  if (tid == 0){
    float g = 0.f;
#pragma unroll
    for (int q = 0; q < 8; ++q) g += sr8[q];
    partial[gid] = g;
    __threadfence();
    int c2 = atomicAdd(&tickets[NGRP], 1);
    if (c2 == NGRP - 1){                     // very last group: final loss
      __threadfence();
      float tot = 0.f;
#pragma unroll
      for (int q = 0; q < NGRP; ++q) tot += partial[q];
      out[0] = -(0.1f / 0.07f) * (tot / (float)N2);
    }
  }
}

// ---- launch ------------------------------------------------------------------
extern "C" void kernel_launch(void* const* d_in, const int* in_sizes, int n_in,
                              void* d_out, int out_size, void* d_ws, size_t ws_size,
                              hipStream_t stream)
{
  const float* outputs  = (const float*)d_in[0];   // (2B, C) f32
  const float* features = (const float*)d_in[1];   // (B, 2, D) f32 (normalized)
  const float* Y        = (const float*)d_in[2];   // (B, C) f32
  const float* ps       = (const float*)d_in[3];   // (B, C) f32
  float* out = (float*)d_out;                      // [loss, new_target(B*C)]

  char* ws = (char*)d_ws;
  int*    tp     = (int*)(ws);                     // 2048 ints        @ 0
  float*  rowsum = (float*)(ws + 8192);            // 2048 f32         @ 8192
  float*  partial= (float*)(ws + 16384);           // 16 f32           @ 16384
  int*    tickets= (int*)(ws + 16448);             // 17 ints          @ 16448
  float2* gES    = (float2*)(ws + 32768);          // 4096*32 float2 (1 MiB)
  unsigned short* cfb   = (unsigned short*)(ws + 1081344);  // 4096*256 bf16 (2 MiB)
  unsigned short* maskB = (unsigned short*)(ws + 3178496);  // 2048*2048 bf16 (8 MiB)

  k1_softmax_tp<<<B_ / 4, 256, 0, stream>>>(outputs, Y, out + 1, tp, tickets);
  k3_mask<<<B_, 256, 0, stream>>>(Y, ps, tp, features, cfb, maskB, rowsum);
  k4_gemm<<<dim3(NGRP, JSPLIT), 512, 0, stream>>>(cfb, maskB, gES, rowsum,
                                                  partial, tickets, out);
}

// Round 13
// 47.523 us; speedup vs baseline: 3.0798x; 3.0798x over previous
//
#include <hip/hip_runtime.h>
#include <stdint.h>

#define B_   2048
#define C_   1000
#define N2   4096
#define D_   256
#define JSPLIT 32
#define IBLK   256                   // i-rows per k4 block (8 waves x 32)
#define NGRP   (N2 / IBLK)           // 16 i-groups
#define JRNG   (N2 / JSPLIT)         // 128 j-rows per block, staged once

typedef float  f32x4  __attribute__((ext_vector_type(4)));
typedef short  short8 __attribute__((ext_vector_type(8)));

__device__ __forceinline__ float waveSum(float v){
#pragma unroll
  for (int o = 32; o; o >>= 1) v += __shfl_xor(v, o, 64);
  return v;
}
__device__ __forceinline__ float waveMax(float v){
#pragma unroll
  for (int o = 32; o; o >>= 1) v = fmaxf(v, __shfl_xor(v, o, 64));
  return v;
}
__device__ __forceinline__ unsigned short f2bf(float f){
  uint32_t u = __float_as_uint(f);
  u += 0x7fffu + ((u >> 16) & 1u);           // RNE
  return (unsigned short)(u >> 16);
}
__device__ __forceinline__ float bf2f(unsigned short h){
  return __uint_as_float(((uint32_t)h) << 16);
}

// ---- Kernel 1: wave-per-row softmax + tp + new_target (single global pass) ---
__global__ __launch_bounds__(256) void k1_softmax_tp(
    const float* __restrict__ outputs, const float* __restrict__ Y,
    float* __restrict__ nt, int* __restrict__ tp, int* __restrict__ tickets)
{
  if (blockIdx.x == 0 && threadIdx.x < 2)
    tickets[threadIdx.x] = 0;                // reset k5's ticket
  const int w = threadIdx.x >> 6, l = threadIdx.x & 63;
  const int i = blockIdx.x * 4 + w;                    // 0..B_-1
  const float4* o4 = (const float4*)(outputs + (size_t)i * C_);
  const float4* y4 = (const float4*)(Y + (size_t)i * C_);

  float4 ov[4], yv[4];
#pragma unroll
  for (int q = 0; q < 4; ++q){
    int idx = q * 64 + l;
    if (idx < 250){ ov[q] = o4[idx]; yv[q] = y4[idx]; }
    else { ov[q] = make_float4(-3.4e38f,-3.4e38f,-3.4e38f,-3.4e38f);
           yv[q] = make_float4(0.f,0.f,0.f,0.f); }
  }

  float m = -3.4e38f;
#pragma unroll
  for (int q = 0; q < 4; ++q)
    m = fmaxf(m, fmaxf(fmaxf(ov[q].x, ov[q].y), fmaxf(ov[q].z, ov[q].w)));
  m = waveMax(m);

  float s = 0.f, bv = -3.4e38f; int bi = 0x7fffffff;
#pragma unroll
  for (int q = 0; q < 4; ++q){
    int c0 = (q * 64 + l) * 4;
    const float* op = (const float*)&ov[q];
    const float* yp = (const float*)&yv[q];
#pragma unroll
    for (int r = 0; r < 4; ++r){
      if (yp[r] > 0.f){
        float oc = op[r];
        s += __expf(oc - m);
        if (oc > bv || (oc == bv && c0 + r < bi)){ bv = oc; bi = c0 + r; }
      }
    }
  }
  s = waveSum(s);
#pragma unroll
  for (int off = 32; off; off >>= 1){
    float ovv = __shfl_xor(bv, off, 64);
    int   oii = __shfl_xor(bi, off, 64);
    if (ovv > bv || (ovv == bv && oii < bi)){ bv = ovv; bi = oii; }
  }

  const float inv = 1.f / s;
  float4* nt4 = (float4*)(nt + (size_t)i * C_);        // i*1000 % 4 == 0: aligned
#pragma unroll
  for (int q = 0; q < 4; ++q){
    int idx = q * 64 + l;
    if (idx < 250){
      const float* op = (const float*)&ov[q];
      const float* yp = (const float*)&yv[q];
      float4 res;
      res.x = (yp[0] > 0.f) ? __expf(op[0] - m) * inv : 0.f;
      res.y = (yp[1] > 0.f) ? __expf(op[1] - m) * inv : 0.f;
      res.z = (yp[2] > 0.f) ? __expf(op[2] - m) * inv : 0.f;
      res.w = (yp[3] > 0.f) ? __expf(op[3] - m) * inv : 0.f;
      nt4[idx] = res;
    }
  }
  if (l == 0){
    if (bi < 0 || bi >= C_) bi = 0;
    tp[i] = bi;
  }
}

// ---- Kernel 3: maskB (bf16) + rowsum + cf->bf16; LDS-staged row gathers ------
__global__ __launch_bounds__(256) void k3_mask(
    const float* __restrict__ Y, const float* __restrict__ ps,
    const int* __restrict__ tp,
    const float* __restrict__ feat, unsigned short* __restrict__ cfb,
    unsigned short* __restrict__ maskB, float* __restrict__ rowsum)
{
  __shared__ int h[C_];
  __shared__ float4 yrow4[250], prow4[250];
  const float* yr = (const float*)yrow4;
  const float* pr = (const float*)prow4;
  const int i = blockIdx.x, t = threadIdx.x;

  // fold: convert flat cfb elements [i*512, i*512+512), vectorized (t<128)
  if (t < 128){
    int idx0 = i * 512 + t * 4;
    int r = idx0 >> 8, d = idx0 & 255;
    int src = (r < B_) ? (r * 512 + d) : ((r - B_) * 512 + 256 + d);
    float4 f = *reinterpret_cast<const float4*>(feat + src);
    uint2 pk;
    pk.x = (uint32_t)f2bf(f.x) | ((uint32_t)f2bf(f.y) << 16);
    pk.y = (uint32_t)f2bf(f.z) | ((uint32_t)f2bf(f.w) << 16);
    *reinterpret_cast<uint2*>(cfb + idx0) = pk;
  }

  for (int c = t; c < C_; c += 256) h[c] = 0;
  __syncthreads();
  // coalesced row staging into LDS (float4)
  if (t < 250){
    yrow4[t] = ((const float4*)(Y  + (size_t)i * C_))[t];
    prow4[t] = ((const float4*)(ps + (size_t)i * C_))[t];
  }
  const int4 t0 = ((const int4*)tp)[t];          // j = 4t .. 4t+3
  const int4 t1 = ((const int4*)tp)[t + 256];    // j = 1024+4t ..
  atomicAdd(&h[t0.x], 1); atomicAdd(&h[t0.y], 1);
  atomicAdd(&h[t0.z], 1); atomicAdd(&h[t0.w], 1);
  atomicAdd(&h[t1.x], 1); atomicAdd(&h[t1.y], 1);
  atomicAdd(&h[t1.z], 1); atomicAdd(&h[t1.w], 1);
  __syncthreads();

  float v0[4], v1[4];
  v0[0] = yr[t0.x] * pr[t0.x] / (float)h[t0.x];
  v0[1] = yr[t0.y] * pr[t0.y] / (float)h[t0.y];
  v0[2] = yr[t0.z] * pr[t0.z] / (float)h[t0.z];
  v0[3] = yr[t0.w] * pr[t0.w] / (float)h[t0.w];
  v1[0] = yr[t1.x] * pr[t1.x] / (float)h[t1.x];
  v1[1] = yr[t1.y] * pr[t1.y] / (float)h[t1.y];
  v1[2] = yr[t1.z] * pr[t1.z] / (float)h[t1.z];
  v1[3] = yr[t1.w] * pr[t1.w] / (float)h[t1.w];

  uint2 pk0, pk1;
  pk0.x = (uint32_t)f2bf(v0[0]) | ((uint32_t)f2bf(v0[1]) << 16);
  pk0.y = (uint32_t)f2bf(v0[2]) | ((uint32_t)f2bf(v0[3]) << 16);
  pk1.x = (uint32_t)f2bf(v1[0]) | ((uint32_t)f2bf(v1[1]) << 16);
  pk1.y = (uint32_t)f2bf(v1[2]) | ((uint32_t)f2bf(v1[3]) << 16);
  ((uint2*)(maskB + (size_t)i * B_))[t]       = pk0;
  ((uint2*)(maskB + (size_t)i * B_))[t + 256] = pk1;

  float loc = (v0[0] + v0[1] + v0[2] + v0[3]) + (v1[0] + v1[1] + v1[2] + v1[3]);
  loc = waveSum(loc);
  __shared__ float sr[4];
  if ((t & 63) == 0) sr[t >> 6] = loc;
  __syncthreads();
  if (t == 0) rowsum[i] = sr[0] + sr[1] + sr[2] + sr[3];
}

// ---- Kernel 4: fused bf16 MFMA GEMM + row reductions -------------------------
// grid (NGRP, JSPLIT), 512 threads (8 waves). Body = r9/r12. NO fused epilogue:
// r10-r12 showed the fused version's per-block device-scope __threadfence()
// (L2 writeback on non-coherent per-XCD L2s) cost ~100us across 512 blocks.
// The kernel-boundary flush gives k5 coherence once, for free.
__global__ __launch_bounds__(512, 2) void k4_gemm(
    const unsigned short* __restrict__ cfb, const unsigned short* __restrict__ maskB,
    float2* __restrict__ gES)
{
  __shared__ uint4 lds4[4096];               // 128 rows x 512 B = 64 KiB
  const int tid = threadIdx.x;
  const int w = tid >> 6;
  const int l = tid & 63;
  const int Ib = blockIdx.x * IBLK;
  const int Jb = blockIdx.y * JRNG;
  const int iA0 = Ib + w * 32 + (l & 15);           // A-tile0 row this lane loads
  const int irow0 = Ib + w * 32 + ((l >> 4) << 2);  // D-tile0 first output i-row

  // async global->LDS staging (dwordx4), pre-swizzled source, linear LDS dest
#pragma unroll
  for (int rep = 0; rep < 8; ++rep){
    int q    = tid + (rep << 9);
    int rowl = q >> 5;
    int c16  = (q & 31) ^ (rowl & 7);        // pre-swizzled source slot
    const unsigned short* gsrc =
        cfb + ((size_t)(Jb + rowl) << 8) + (c16 << 3);
    uint4* ldst = &lds4[(rep << 9) + (w << 6)];      // wave-uniform base
    __builtin_amdgcn_global_load_lds(
        (const __attribute__((address_space(1))) void*)gsrc,
        (__attribute__((address_space(3))) void*)ldst, 16, 0, 0);
  }

  short8 afrag0[8], afrag1[8];
#pragma unroll
  for (int kk = 0; kk < 8; ++kk){
    afrag0[kk] = *reinterpret_cast<const short8*>(
        cfb + ((size_t)iA0 << 8) + (kk << 5) + ((l >> 4) << 3));
    afrag1[kk] = *reinterpret_cast<const short8*>(
        cfb + ((size_t)(iA0 + 16) << 8) + (kk << 5) + ((l >> 4) << 3));
  }

  __syncthreads();                           // the ONLY barrier

  float E0[4]  = {0.f,0.f,0.f,0.f}, S10[4] = {0.f,0.f,0.f,0.f};
  float E1[4]  = {0.f,0.f,0.f,0.f}, S11[4] = {0.f,0.f,0.f,0.f};

#pragma unroll
  for (int s = 0; s < JRNG / 16; ++s){       // 8 independent steps
    f32x4 a0 = {0.f,0.f,0.f,0.f};
    f32x4 a1 = {0.f,0.f,0.f,0.f};
    const int brow = s * 16 + (l & 15);      // j-row of LDS tile (B operand)
#pragma unroll
    for (int kk = 0; kk < 8; ++kk){
      int idx16 = brow * 32 + ((kk * 4 + (l >> 4)) ^ (l & 7));
      short8 bfr = *reinterpret_cast<const short8*>(&lds4[idx16]);
      a0 = __builtin_amdgcn_mfma_f32_16x16x32_bf16(afrag0[kk], bfr, a0, 0, 0, 0);
      a1 = __builtin_amdgcn_mfma_f32_16x16x32_bf16(afrag1[kk], bfr, a1, 0, 0, 0);
    }
    const int j  = Jb + s * 16 + (l & 15);
    const int jp = j & (B_ - 1);
#pragma unroll
    for (int r = 0; r < 4; ++r){
      {
        const int ir  = irow0 + r;
        const int ipr = ir & (B_ - 1);
        float mv = bf2f(maskB[(size_t)ipr * B_ + jp]);   // coalesced over l&15
        float d = a0[r] * 10.f;              // adc = dot / T
        if (j != ir){                        // skip exact diagonal
          E0[r]  += __expf(d - 10.f);        // M = 10 (row max = diagonal)
          S10[r] += mv * d;
        }
      }
      {
        const int ir  = irow0 + 16 + r;
        const int ipr = ir & (B_ - 1);
        float mv = bf2f(maskB[(size_t)ipr * B_ + jp]);
        float d = a1[r] * 10.f;
        if (j != ir){
          E1[r]  += __expf(d - 10.f);
          S11[r] += mv * d;
        }
      }
    }
  }

  // reduce across the 16 lanes of each quadrant (same output i-row set)
#pragma unroll
  for (int r = 0; r < 4; ++r){
    float e0 = E0[r], s0 = S10[r], e1 = E1[r], s1 = S11[r];
#pragma unroll
    for (int off = 1; off < 16; off <<= 1){
      e0 += __shfl_xor(e0, off, 64);  s0 += __shfl_xor(s0, off, 64);
      e1 += __shfl_xor(e1, off, 64);  s1 += __shfl_xor(s1, off, 64);
    }
    if ((l & 15) == 0){
      gES[(size_t)(irow0 + r)      * JSPLIT + blockIdx.y] = make_float2(e0, s0);
      gES[(size_t)(irow0 + 16 + r) * JSPLIT + blockIdx.y] = make_float2(e1, s1);
    }
  }
}

// ---- Kernel 5: per-row combine + last-block final loss (r9 proven) -----------
__global__ __launch_bounds__(256) void k5_rows(
    const float2* __restrict__ gES, const float* __restrict__ rowsum,
    const unsigned short* __restrict__ maskB, float* __restrict__ partial,
    int* __restrict__ ticket, float* __restrict__ out)
{
  const int i = blockIdx.x * 256 + threadIdx.x;      // 0..N2-1
  const float2* vv = gES + (size_t)i * JSPLIT;
  float E = 0.f, S1 = 0.f;
#pragma unroll 4
  for (int q = 0; q < JSPLIT; ++q){
    float2 t = vv[q];
    E  += t.x;
    S1 += t.y;
  }
  int ipp = i & (B_ - 1);
  float msum = 2.f * rowsum[ipp] - bf2f(maskB[(size_t)ipp * B_ + ipp]);
  float loc = S1 - msum * (10.f + __logf(E));  // contrib with M=10

  loc = waveSum(loc);
  __shared__ float sr[4];
  if ((threadIdx.x & 63) == 0) sr[threadIdx.x >> 6] = loc;
  __syncthreads();
  if (threadIdx.x == 0){
    partial[blockIdx.x] = sr[0] + sr[1] + sr[2] + sr[3];
    __threadfence();
    int tk = atomicAdd(ticket, 1);
    if (tk == (N2 / 256) - 1){               // last block: fixed-order final sum
      __threadfence();
      float tot = 0.f;
#pragma unroll
      for (int q = 0; q < N2 / 256; ++q) tot += partial[q];
      out[0] = -(0.1f / 0.07f) * (tot / (float)N2);
    }
  }
}

// ---- launch ------------------------------------------------------------------
extern "C" void kernel_launch(void* const* d_in, const int* in_sizes, int n_in,
                              void* d_out, int out_size, void* d_ws, size_t ws_size,
                              hipStream_t stream)
{
  const float* outputs  = (const float*)d_in[0];   // (2B, C) f32
  const float* features = (const float*)d_in[1];   // (B, 2, D) f32 (normalized)
  const float* Y        = (const float*)d_in[2];   // (B, C) f32
  const float* ps       = (const float*)d_in[3];   // (B, C) f32
  float* out = (float*)d_out;                      // [loss, new_target(B*C)]

  char* ws = (char*)d_ws;
  int*    tp     = (int*)(ws);                     // 2048 ints        @ 0
  float*  rowsum = (float*)(ws + 8192);            // 2048 f32         @ 8192
  float*  partial= (float*)(ws + 16384);           // 16 f32           @ 16384
  int*    tickets= (int*)(ws + 16448);             // 2 ints           @ 16448
  float2* gES    = (float2*)(ws + 32768);          // 4096*32 float2 (1 MiB)
  unsigned short* cfb   = (unsigned short*)(ws + 1081344);  // 4096*256 bf16 (2 MiB)
  unsigned short* maskB = (unsigned short*)(ws + 3178496);  // 2048*2048 bf16 (8 MiB)

  k1_softmax_tp<<<B_ / 4, 256, 0, stream>>>(outputs, Y, out + 1, tp, tickets);
  k3_mask<<<B_, 256, 0, stream>>>(Y, ps, tp, features, cfb, maskB, rowsum);
  k4_gemm<<<dim3(NGRP, JSPLIT), 512, 0, stream>>>(cfb, maskB, gES);
  k5_rows<<<N2 / 256, 256, 0, stream>>>(gES, rowsum, maskB, partial, tickets, out);
}